// Round 1
// baseline (5930.085 us; speedup 1.0000x reference)
//
#include <hip/hip_runtime.h>
#include <hip/hip_bf16.h>

#define N_NODES 50000
#define N_EDGES 800000

// ---------------- degree / normalization ----------------

__global__ __launch_bounds__(256) void zero_kernel(float* p, int n) {
    int i = blockIdx.x * blockDim.x + threadIdx.x;
    if (i < n) p[i] = 0.f;
}

__global__ __launch_bounds__(256) void deg_kernel(const int* __restrict__ dst,
                                                  const float* __restrict__ ew,
                                                  float* __restrict__ deg, int E) {
    int e = blockIdx.x * blockDim.x + threadIdx.x;
    if (e < E) atomicAdd(&deg[dst[e]], ew[e]);
}

__global__ __launch_bounds__(256) void dinv_kernel(float* __restrict__ deg, int n) {
    int i = blockIdx.x * blockDim.x + threadIdx.x;
    if (i < n) deg[i] = rsqrtf(deg[i] + 1.0f);
}

// ---------------- self-loop init (+optional bias) ----------------
// agg[i][c] = dinv[i]^2 * t[i][c] (+ bias[c])

template <int C, bool BIAS>
__global__ __launch_bounds__(256) void self_init_kernel(const float* __restrict__ t,
                                                        const float* __restrict__ dinv,
                                                        const float* __restrict__ bias,
                                                        float* __restrict__ agg, int n) {
    constexpr int C4 = C >> 2;
    int idx = blockIdx.x * blockDim.x + threadIdx.x;
    if (idx >= n * C4) return;
    int i = idx / C4, c4 = idx % C4;
    float di = dinv[i];
    float s = di * di;
    float4 v = ((const float4*)(t + (size_t)i * C))[c4];
    float4 r;
    if (BIAS) {
        float4 b4 = ((const float4*)bias)[c4];
        r.x = s * v.x + b4.x; r.y = s * v.y + b4.y;
        r.z = s * v.z + b4.z; r.w = s * v.w + b4.w;
    } else {
        r.x = s * v.x; r.y = s * v.y; r.z = s * v.z; r.w = s * v.w;
    }
    ((float4*)(agg + (size_t)i * C))[c4] = r;
}

// ---------------- edge scatter-add ----------------
// agg[dst] += dinv[src]*ew*dinv[dst] * t[src]

template <int C>
__global__ __launch_bounds__(256) void scatter_kernel(const float* __restrict__ t,
                                                      float* __restrict__ agg,
                                                      const int* __restrict__ src,
                                                      const int* __restrict__ dst,
                                                      const float* __restrict__ ew,
                                                      const float* __restrict__ dinv, int E) {
    constexpr int C4 = C >> 2;
    int idx = blockIdx.x * blockDim.x + threadIdx.x;
    if (idx >= E * C4) return;
    int e = idx / C4, c4 = idx % C4;
    int s = src[e], d = dst[e];
    float w = dinv[s] * ew[e] * dinv[d];
    float4 v = ((const float4*)(t + (size_t)s * C))[c4];
    float* o = agg + (size_t)d * C + (size_t)c4 * 4;
    atomicAdd(o + 0, w * v.x);
    atomicAdd(o + 1, w * v.y);
    atomicAdd(o + 2, w * v.z);
    atomicAdd(o + 3, w * v.w);
}

// ---------------- fp32 tiled GEMM: C = op(A) @ B (+bias) (+relu) ----------------
// A: [M,K] row-major, B: [K,N] row-major, C: [M,N]. K % 16 == 0, N % 64 == 0.

template <bool RELU_IN, bool BIAS, bool RELU_OUT>
__global__ __launch_bounds__(256) void gemm_kernel(const float* __restrict__ A,
                                                   const float* __restrict__ B,
                                                   const float* __restrict__ bias,
                                                   float* __restrict__ Cmat,
                                                   int M, int K, int N) {
    __shared__ float As[16][64];  // As[k][m]
    __shared__ float Bs[16][64];  // Bs[k][n]
    int tid = threadIdx.x;
    int bx = blockIdx.x, by = blockIdx.y;
    int tx = tid & 15, ty = tid >> 4;

    float acc[4][4] = {};

    int arow_l = tid >> 2;            // 0..63
    int acol4 = (tid & 3) * 4;        // 0,4,8,12
    int arow = by * 64 + arow_l;
    int brow = tid >> 4;              // 0..15
    int bcol4 = (tid & 15) * 4;
    int bcol = bx * 64 + bcol4;

    for (int k0 = 0; k0 < K; k0 += 16) {
        float4 av = {0.f, 0.f, 0.f, 0.f};
        if (arow < M) av = *(const float4*)(A + (size_t)arow * K + k0 + acol4);
        if (RELU_IN) {
            av.x = fmaxf(av.x, 0.f); av.y = fmaxf(av.y, 0.f);
            av.z = fmaxf(av.z, 0.f); av.w = fmaxf(av.w, 0.f);
        }
        As[acol4 + 0][arow_l] = av.x;
        As[acol4 + 1][arow_l] = av.y;
        As[acol4 + 2][arow_l] = av.z;
        As[acol4 + 3][arow_l] = av.w;
        float4 bv = *(const float4*)(B + (size_t)(k0 + brow) * N + bcol);
        *(float4*)&Bs[brow][bcol4] = bv;
        __syncthreads();
#pragma unroll
        for (int k = 0; k < 16; ++k) {
            float4 a = *(const float4*)&As[k][ty * 4];
            float4 b = *(const float4*)&Bs[k][tx * 4];
            float ar[4] = {a.x, a.y, a.z, a.w};
            float br[4] = {b.x, b.y, b.z, b.w};
#pragma unroll
            for (int i = 0; i < 4; ++i)
#pragma unroll
                for (int j = 0; j < 4; ++j)
                    acc[i][j] = fmaf(ar[i], br[j], acc[i][j]);
        }
        __syncthreads();
    }

    int crow = by * 64 + ty * 4;
    int ccol = bx * 64 + tx * 4;
    float4 b4 = {0.f, 0.f, 0.f, 0.f};
    if (BIAS) b4 = *(const float4*)&bias[ccol];
#pragma unroll
    for (int i = 0; i < 4; ++i) {
        if (crow + i < M) {
            float4 r;
            r.x = acc[i][0] + b4.x; r.y = acc[i][1] + b4.y;
            r.z = acc[i][2] + b4.z; r.w = acc[i][3] + b4.w;
            if (RELU_OUT) {
                r.x = fmaxf(r.x, 0.f); r.y = fmaxf(r.y, 0.f);
                r.z = fmaxf(r.z, 0.f); r.w = fmaxf(r.w, 0.f);
            }
            *(float4*)(Cmat + (size_t)(crow + i) * N + ccol) = r;
        }
    }
}

// ---------------- fused MLP head + softmax ----------------
// in: h (pre-relu, [N,128]); out: softmax(relu(relu(relu(h)W1+b1)W2+b2)W3+b3)

__global__ __launch_bounds__(256) void mlp_kernel(const float* __restrict__ h,
                                                  const float* __restrict__ W1, const float* __restrict__ b1,
                                                  const float* __restrict__ W2, const float* __restrict__ b2,
                                                  const float* __restrict__ W3, const float* __restrict__ b3,
                                                  float* __restrict__ out, int n) {
    __shared__ float W1s[128 * 64];
    __shared__ float W2s[64 * 32];
    __shared__ float W3s[32 * 40];
    __shared__ float b1s[64], b2s[32], b3s[40];
    __shared__ float hs[4][128];
    __shared__ float h1s[4][64];
    __shared__ float h2s[4][32];
    __shared__ float ls[4][40];
    __shared__ float es[4][40];

    int tid = threadIdx.x;
    for (int i = tid; i < 128 * 64; i += 256) W1s[i] = W1[i];
    for (int i = tid; i < 64 * 32; i += 256) W2s[i] = W2[i];
    for (int i = tid; i < 32 * 40; i += 256) W3s[i] = W3[i];
    if (tid < 64) b1s[tid] = b1[tid];
    if (tid < 32) b2s[tid] = b2[tid];
    if (tid < 40) b3s[tid] = b3[tid];
    __syncthreads();

    int wave = tid >> 6, lane = tid & 63;

    for (int base = blockIdx.x * 4; base < n; base += gridDim.x * 4) {
        int node = base + wave;
        if (node < n) {
            hs[wave][lane]      = fmaxf(h[(size_t)node * 128 + lane], 0.f);
            hs[wave][lane + 64] = fmaxf(h[(size_t)node * 128 + lane + 64], 0.f);
        }
        __syncthreads();
        // L1: 128 -> 64 (all 64 lanes)
        {
            float acc = b1s[lane];
#pragma unroll 8
            for (int k = 0; k < 128; ++k) acc += hs[wave][k] * W1s[k * 64 + lane];
            h1s[wave][lane] = fmaxf(acc, 0.f);
        }
        __syncthreads();
        // L2: 64 -> 32
        if (lane < 32) {
            float acc = b2s[lane];
#pragma unroll 8
            for (int k = 0; k < 64; ++k) acc += h1s[wave][k] * W2s[k * 32 + lane];
            h2s[wave][lane] = fmaxf(acc, 0.f);
        }
        __syncthreads();
        // L3: 32 -> 40 logits
        if (lane < 40) {
            float acc = b3s[lane];
#pragma unroll 8
            for (int k = 0; k < 32; ++k) acc += h2s[wave][k] * W3s[k * 40 + lane];
            ls[wave][lane] = acc;
        }
        __syncthreads();
        float e = 0.f;
        if (lane < 40) {
            float m = -1e30f;
            for (int j = 0; j < 40; ++j) m = fmaxf(m, ls[wave][j]);
            e = expf(ls[wave][lane] - m);
            es[wave][lane] = e;
        }
        __syncthreads();
        if (node < n && lane < 40) {
            float s = 0.f;
            for (int j = 0; j < 40; ++j) s += es[wave][j];
            out[(size_t)node * 40 + lane] = e / s;
        }
        __syncthreads();
    }
}

// ---------------- launcher ----------------

extern "C" void kernel_launch(void* const* d_in, const int* in_sizes, int n_in,
                              void* d_out, int out_size, void* d_ws, size_t ws_size,
                              hipStream_t stream) {
    const float* x   = (const float*)d_in[0];
    const int*   ei  = (const int*)d_in[1];
    const float* ew  = (const float*)d_in[2];
    const float* W1  = (const float*)d_in[3];
    const float* b1  = (const float*)d_in[4];
    const float* W2  = (const float*)d_in[5];
    const float* b2  = (const float*)d_in[6];
    const float* W3  = (const float*)d_in[7];
    const float* b3  = (const float*)d_in[8];
    const float* L1w = (const float*)d_in[9];
    const float* L1b = (const float*)d_in[10];
    const float* L2w = (const float*)d_in[11];
    const float* L2b = (const float*)d_in[12];
    const float* L3w = (const float*)d_in[13];
    const float* L3b = (const float*)d_in[14];
    float* out = (float*)d_out;

    const int n = N_NODES, E = N_EDGES;
    const int* src = ei;
    const int* dst = ei + E;

    float* ws = (float*)d_ws;
    // workspace layout (floats)
    float* dinv = ws;                                   // 50000 (use 51200 slot)
    float* aggX = ws + 51200;                           // 50000*128 = 6,400,000 ; reused as t3
    float* h1   = ws + 51200 + 6400000;                 // 50000*512 = 25,600,000 ; reused as agg3
    float* t2   = ws + 51200 + 6400000 + 25600000;      // 50000*256 = 12,800,000
    float* agg2 = t2 + 12800000;                        // 50000*256 = 12,800,000
    float* t3   = aggX;
    float* agg3 = h1;

    // deg / dinv
    zero_kernel<<<(n + 255) / 256, 256, 0, stream>>>(dinv, n);
    deg_kernel<<<(E + 255) / 256, 256, 0, stream>>>(dst, ew, dinv, E);
    dinv_kernel<<<(n + 255) / 256, 256, 0, stream>>>(dinv, n);

    // ----- layer 1: aggX = A_hat x ; h1 = relu(aggX @ W1 + b1)
    self_init_kernel<128, false><<<(n * 32 + 255) / 256, 256, 0, stream>>>(x, dinv, nullptr, aggX, n);
    scatter_kernel<128><<<(E * 32 + 255) / 256, 256, 0, stream>>>(x, aggX, src, dst, ew, dinv, E);
    {
        dim3 g(512 / 64, (n + 63) / 64);
        gemm_kernel<false, true, true><<<g, 256, 0, stream>>>(aggX, W1, b1, h1, n, 128, 512);
    }
    // ----- layer 2: t2 = h1 @ W2 ; agg2 = A_hat t2 + b2
    {
        dim3 g(256 / 64, (n + 63) / 64);
        gemm_kernel<false, false, false><<<g, 256, 0, stream>>>(h1, W2, nullptr, t2, n, 512, 256);
    }
    self_init_kernel<256, true><<<(n * 64 + 255) / 256, 256, 0, stream>>>(t2, dinv, b2, agg2, n);
    scatter_kernel<256><<<(E * 64 + 255) / 256, 256, 0, stream>>>(t2, agg2, src, dst, ew, dinv, E);
    // ----- layer 3: t3 = relu(agg2) @ W3 ; agg3 = A_hat t3 + b3
    {
        dim3 g(128 / 64, (n + 63) / 64);
        gemm_kernel<true, false, false><<<g, 256, 0, stream>>>(agg2, W3, nullptr, t3, n, 256, 128);
    }
    self_init_kernel<128, true><<<(n * 32 + 255) / 256, 256, 0, stream>>>(t3, dinv, b3, agg3, n);
    scatter_kernel<128><<<(E * 32 + 255) / 256, 256, 0, stream>>>(t3, agg3, src, dst, ew, dinv, E);
    // ----- MLP head + softmax
    mlp_kernel<<<1024, 256, 0, stream>>>(agg3, L1w, L1b, L2w, L2b, L3w, L3b, out, n);
}

// Round 2
// 996.643 us; speedup vs baseline: 5.9501x; 5.9501x over previous
//
#include <hip/hip_runtime.h>
#include <hip/hip_bf16.h>

#define N_NODES 50000
#define N_EDGES 800000

// ---------------- degree / normalization ----------------

__global__ __launch_bounds__(256) void deg_kernel(const int* __restrict__ dst,
                                                  const float* __restrict__ ew,
                                                  float* __restrict__ deg, int E) {
    int e = blockIdx.x * blockDim.x + threadIdx.x;
    if (e < E) atomicAdd(&deg[dst[e]], ew[e]);
}

__global__ __launch_bounds__(256) void dinv_kernel(float* __restrict__ deg, int n) {
    int i = blockIdx.x * blockDim.x + threadIdx.x;
    if (i < n) deg[i] = rsqrtf(deg[i] + 1.0f);
}

// ---------------- CSR build ----------------

__global__ __launch_bounds__(256) void count_kernel(const int* __restrict__ dst,
                                                    int* __restrict__ cnt, int E) {
    int e = blockIdx.x * blockDim.x + threadIdx.x;
    if (e < E) atomicAdd(&cnt[dst[e]], 1);
}

// block b scans cnt[b*512 .. b*512+512) inclusively -> rowptr[i+1]; bsums[b]=block total
__global__ __launch_bounds__(512) void scan_block_kernel(const int* __restrict__ cnt,
                                                         int* __restrict__ rowptr,
                                                         int* __restrict__ bsums, int n) {
    __shared__ int s[512];
    int t = threadIdx.x;
    int i = blockIdx.x * 512 + t;
    s[t] = (i < n) ? cnt[i] : 0;
    __syncthreads();
    for (int off = 1; off < 512; off <<= 1) {
        int v = (t >= off) ? s[t - off] : 0;
        __syncthreads();
        s[t] += v;
        __syncthreads();
    }
    if (i < n) rowptr[i + 1] = s[t];
    if (t == 511) bsums[blockIdx.x] = s[511];
}

__global__ void scan_sums_kernel(int* bsums, int nb) {
    if (threadIdx.x == 0 && blockIdx.x == 0) {
        int run = 0;
        for (int i = 0; i < nb; ++i) { int v = bsums[i]; bsums[i] = run; run += v; }
    }
}

__global__ __launch_bounds__(512) void scan_add_kernel(int* __restrict__ rowptr,
                                                       const int* __restrict__ bsums, int n) {
    int i = blockIdx.x * 512 + threadIdx.x;
    if (i < n) rowptr[i + 1] += bsums[blockIdx.x];
    if (i == 0) rowptr[0] = 0;
}

// cursor starts as copy of rowptr[0..n); per-edge coeff = dinv[src]*ew
__global__ __launch_bounds__(256) void fill_kernel(const int* __restrict__ src,
                                                   const int* __restrict__ dst,
                                                   const float* __restrict__ ew,
                                                   const float* __restrict__ dinv,
                                                   int* __restrict__ cursor,
                                                   int* __restrict__ col,
                                                   float* __restrict__ val, int E) {
    int e = blockIdx.x * blockDim.x + threadIdx.x;
    if (e >= E) return;
    int d = dst[e];
    int s = src[e];
    int pos = atomicAdd(&cursor[d], 1);
    col[pos] = s;
    val[pos] = dinv[s] * ew[e];
}

// ---------------- CSR gather aggregation ----------------
// out[i] = dinv[i] * sum_e val_e * t[col_e] + dinv[i]^2 * t[i] (+ bias)

template <int C, bool BIAS>
__global__ __launch_bounds__(256) void gather_kernel(const float* __restrict__ t,
                                                     const int* __restrict__ rowptr,
                                                     const int* __restrict__ col,
                                                     const float* __restrict__ val,
                                                     const float* __restrict__ dinv,
                                                     const float* __restrict__ bias,
                                                     float* __restrict__ outp, int n) {
    constexpr int R = C / 64;
    int wave = threadIdx.x >> 6, lane = threadIdx.x & 63;
    for (int node = blockIdx.x * 4 + wave; node < n; node += gridDim.x * 4) {
        float acc[R];
#pragma unroll
        for (int r = 0; r < R; ++r) acc[r] = 0.f;
        int p0 = rowptr[node], p1 = rowptr[node + 1];
        for (int p = p0; p < p1; ++p) {
            int s = col[p];
            float a = val[p];
            const float* tr = t + (size_t)s * C;
#pragma unroll
            for (int r = 0; r < R; ++r) acc[r] += a * tr[r * 64 + lane];
        }
        float di = dinv[node];
        const float* tn = t + (size_t)node * C;
        float* o = outp + (size_t)node * C;
#pragma unroll
        for (int r = 0; r < R; ++r) {
            float v = di * acc[r] + di * di * tn[r * 64 + lane];
            if (BIAS) v += bias[r * 64 + lane];
            o[r * 64 + lane] = v;
        }
    }
}

// ---------------- fp32 tiled GEMM: C = op(A) @ B (+bias) (+relu) ----------------

template <bool RELU_IN, bool BIAS, bool RELU_OUT>
__global__ __launch_bounds__(256) void gemm_kernel(const float* __restrict__ A,
                                                   const float* __restrict__ B,
                                                   const float* __restrict__ bias,
                                                   float* __restrict__ Cmat,
                                                   int M, int K, int N) {
    __shared__ float As[16][64];  // As[k][m]
    __shared__ float Bs[16][64];  // Bs[k][n]
    int tid = threadIdx.x;
    int bx = blockIdx.x, by = blockIdx.y;
    int tx = tid & 15, ty = tid >> 4;

    float acc[4][4] = {};

    int arow_l = tid >> 2;
    int acol4 = (tid & 3) * 4;
    int arow = by * 64 + arow_l;
    int brow = tid >> 4;
    int bcol4 = (tid & 15) * 4;
    int bcol = bx * 64 + bcol4;

    for (int k0 = 0; k0 < K; k0 += 16) {
        float4 av = {0.f, 0.f, 0.f, 0.f};
        if (arow < M) av = *(const float4*)(A + (size_t)arow * K + k0 + acol4);
        if (RELU_IN) {
            av.x = fmaxf(av.x, 0.f); av.y = fmaxf(av.y, 0.f);
            av.z = fmaxf(av.z, 0.f); av.w = fmaxf(av.w, 0.f);
        }
        As[acol4 + 0][arow_l] = av.x;
        As[acol4 + 1][arow_l] = av.y;
        As[acol4 + 2][arow_l] = av.z;
        As[acol4 + 3][arow_l] = av.w;
        float4 bv = *(const float4*)(B + (size_t)(k0 + brow) * N + bcol);
        *(float4*)&Bs[brow][bcol4] = bv;
        __syncthreads();
#pragma unroll
        for (int k = 0; k < 16; ++k) {
            float4 a = *(const float4*)&As[k][ty * 4];
            float4 b = *(const float4*)&Bs[k][tx * 4];
            float ar[4] = {a.x, a.y, a.z, a.w};
            float br[4] = {b.x, b.y, b.z, b.w};
#pragma unroll
            for (int i = 0; i < 4; ++i)
#pragma unroll
                for (int j = 0; j < 4; ++j)
                    acc[i][j] = fmaf(ar[i], br[j], acc[i][j]);
        }
        __syncthreads();
    }

    int crow = by * 64 + ty * 4;
    int ccol = bx * 64 + tx * 4;
    float4 b4 = {0.f, 0.f, 0.f, 0.f};
    if (BIAS) b4 = *(const float4*)&bias[ccol];
#pragma unroll
    for (int i = 0; i < 4; ++i) {
        if (crow + i < M) {
            float4 r;
            r.x = acc[i][0] + b4.x; r.y = acc[i][1] + b4.y;
            r.z = acc[i][2] + b4.z; r.w = acc[i][3] + b4.w;
            if (RELU_OUT) {
                r.x = fmaxf(r.x, 0.f); r.y = fmaxf(r.y, 0.f);
                r.z = fmaxf(r.z, 0.f); r.w = fmaxf(r.w, 0.f);
            }
            *(float4*)(Cmat + (size_t)(crow + i) * N + ccol) = r;
        }
    }
}

// ---------------- fused MLP head + softmax ----------------

__global__ __launch_bounds__(256) void mlp_kernel(const float* __restrict__ h,
                                                  const float* __restrict__ W1, const float* __restrict__ b1,
                                                  const float* __restrict__ W2, const float* __restrict__ b2,
                                                  const float* __restrict__ W3, const float* __restrict__ b3,
                                                  float* __restrict__ out, int n) {
    __shared__ float W1s[128 * 64];
    __shared__ float W2s[64 * 32];
    __shared__ float W3s[32 * 40];
    __shared__ float b1s[64], b2s[32], b3s[40];
    __shared__ float hs[4][128];
    __shared__ float h1s[4][64];
    __shared__ float h2s[4][32];
    __shared__ float ls[4][40];
    __shared__ float es[4][40];

    int tid = threadIdx.x;
    for (int i = tid; i < 128 * 64; i += 256) W1s[i] = W1[i];
    for (int i = tid; i < 64 * 32; i += 256) W2s[i] = W2[i];
    for (int i = tid; i < 32 * 40; i += 256) W3s[i] = W3[i];
    if (tid < 64) b1s[tid] = b1[tid];
    if (tid < 32) b2s[tid] = b2[tid];
    if (tid < 40) b3s[tid] = b3[tid];
    __syncthreads();

    int wave = tid >> 6, lane = tid & 63;

    for (int base = blockIdx.x * 4; base < n; base += gridDim.x * 4) {
        int node = base + wave;
        if (node < n) {
            hs[wave][lane]      = fmaxf(h[(size_t)node * 128 + lane], 0.f);
            hs[wave][lane + 64] = fmaxf(h[(size_t)node * 128 + lane + 64], 0.f);
        }
        __syncthreads();
        {
            float acc = b1s[lane];
#pragma unroll 8
            for (int k = 0; k < 128; ++k) acc += hs[wave][k] * W1s[k * 64 + lane];
            h1s[wave][lane] = fmaxf(acc, 0.f);
        }
        __syncthreads();
        if (lane < 32) {
            float acc = b2s[lane];
#pragma unroll 8
            for (int k = 0; k < 64; ++k) acc += h1s[wave][k] * W2s[k * 32 + lane];
            h2s[wave][lane] = fmaxf(acc, 0.f);
        }
        __syncthreads();
        if (lane < 40) {
            float acc = b3s[lane];
#pragma unroll 8
            for (int k = 0; k < 32; ++k) acc += h2s[wave][k] * W3s[k * 40 + lane];
            ls[wave][lane] = acc;
        }
        __syncthreads();
        float e = 0.f;
        if (lane < 40) {
            float m = -1e30f;
            for (int j = 0; j < 40; ++j) m = fmaxf(m, ls[wave][j]);
            e = expf(ls[wave][lane] - m);
            es[wave][lane] = e;
        }
        __syncthreads();
        if (node < n && lane < 40) {
            float s = 0.f;
            for (int j = 0; j < 40; ++j) s += es[wave][j];
            out[(size_t)node * 40 + lane] = e / s;
        }
        __syncthreads();
    }
}

// ---------------- launcher ----------------

extern "C" void kernel_launch(void* const* d_in, const int* in_sizes, int n_in,
                              void* d_out, int out_size, void* d_ws, size_t ws_size,
                              hipStream_t stream) {
    const float* x   = (const float*)d_in[0];
    const int*   ei  = (const int*)d_in[1];
    const float* ew  = (const float*)d_in[2];
    const float* W1  = (const float*)d_in[3];
    const float* b1  = (const float*)d_in[4];
    const float* W2  = (const float*)d_in[5];
    const float* b2  = (const float*)d_in[6];
    const float* W3  = (const float*)d_in[7];
    const float* b3  = (const float*)d_in[8];
    const float* L1w = (const float*)d_in[9];
    const float* L1b = (const float*)d_in[10];
    const float* L2w = (const float*)d_in[11];
    const float* L2b = (const float*)d_in[12];
    const float* L3w = (const float*)d_in[13];
    const float* L3b = (const float*)d_in[14];
    float* out = (float*)d_out;

    const int n = N_NODES, E = N_EDGES;
    const int* src = ei;
    const int* dst = ei + E;

    // workspace layout (4-byte units)
    float* ws = (float*)d_ws;
    size_t off = 0;
    float* dinv   = ws + off; off += 51200;
    float* aggX   = ws + off; off += (size_t)N_NODES * 128;  // reused as t3
    float* h1     = ws + off; off += (size_t)N_NODES * 512;  // reused as agg3
    float* t2     = ws + off; off += (size_t)N_NODES * 256;
    float* agg2   = ws + off; off += (size_t)N_NODES * 256;
    int*   rowptr = (int*)(ws + off); off += 51200;
    int*   cursor = (int*)(ws + off); off += 51200;          // also the count buffer
    int*   col    = (int*)(ws + off); off += N_EDGES;
    float* val    = ws + off; off += N_EDGES;
    int*   bsums  = (int*)(ws + off); off += 256;
    float* t3   = aggX;
    float* agg3 = h1;

    const int nb = (n + 511) / 512;

    // deg / dinv
    hipMemsetAsync(dinv, 0, n * sizeof(float), stream);
    deg_kernel<<<(E + 255) / 256, 256, 0, stream>>>(dst, ew, dinv, E);
    dinv_kernel<<<(n + 255) / 256, 256, 0, stream>>>(dinv, n);

    // CSR build (by dst)
    hipMemsetAsync(cursor, 0, n * sizeof(int), stream);
    count_kernel<<<(E + 255) / 256, 256, 0, stream>>>(dst, cursor, E);
    scan_block_kernel<<<nb, 512, 0, stream>>>(cursor, rowptr, bsums, n);
    scan_sums_kernel<<<1, 64, 0, stream>>>(bsums, nb);
    scan_add_kernel<<<nb, 512, 0, stream>>>(rowptr, bsums, n);
    hipMemcpyAsync(cursor, rowptr, n * sizeof(int), hipMemcpyDeviceToDevice, stream);
    fill_kernel<<<(E + 255) / 256, 256, 0, stream>>>(src, dst, ew, dinv, cursor, col, val, E);

    // ----- layer 1: aggX = A_hat x ; h1 = relu(aggX @ W1 + b1)
    gather_kernel<128, false><<<(n + 3) / 4, 256, 0, stream>>>(x, rowptr, col, val, dinv, nullptr, aggX, n);
    {
        dim3 g(512 / 64, (n + 63) / 64);
        gemm_kernel<false, true, true><<<g, 256, 0, stream>>>(aggX, W1, b1, h1, n, 128, 512);
    }
    // ----- layer 2: t2 = h1 @ W2 ; agg2 = A_hat t2 + b2
    {
        dim3 g(256 / 64, (n + 63) / 64);
        gemm_kernel<false, false, false><<<g, 256, 0, stream>>>(h1, W2, nullptr, t2, n, 512, 256);
    }
    gather_kernel<256, true><<<(n + 3) / 4, 256, 0, stream>>>(t2, rowptr, col, val, dinv, b2, agg2, n);
    // ----- layer 3: t3 = relu(agg2) @ W3 ; agg3 = A_hat t3 + b3
    {
        dim3 g(128 / 64, (n + 63) / 64);
        gemm_kernel<true, false, false><<<g, 256, 0, stream>>>(agg2, W3, nullptr, t3, n, 256, 128);
    }
    gather_kernel<128, true><<<(n + 3) / 4, 256, 0, stream>>>(t3, rowptr, col, val, dinv, b3, agg3, n);
    // ----- MLP head + softmax
    mlp_kernel<<<1024, 256, 0, stream>>>(agg3, L1w, L1b, L2w, L2b, L3w, L3b, out, n);
}

// Round 4
// 761.942 us; speedup vs baseline: 7.7829x; 1.3080x over previous
//
#include <hip/hip_runtime.h>
#include <hip/hip_bf16.h>

#define N_NODES 50000
#define N_EDGES 800000
#define M_PAD 50048  // 391 * 128

typedef __attribute__((ext_vector_type(8))) short short8;
typedef __attribute__((ext_vector_type(4))) float float4_;

#define GLOAD_LDS(g, l) __builtin_amdgcn_global_load_lds( \
    (const __attribute__((address_space(1))) void*)(g),   \
    (__attribute__((address_space(3))) void*)(l), 16, 0, 0)

__device__ __forceinline__ unsigned short f2bf(float f) {
    unsigned int u = __float_as_uint(f);
    unsigned int r = (u + 0x7FFFu + ((u >> 16) & 1u)) >> 16;
    return (unsigned short)r;
}
__device__ __forceinline__ float bf2f(unsigned short h) {
    return __uint_as_float(((unsigned int)h) << 16);
}

// ---------------- degree / normalization ----------------

__global__ __launch_bounds__(256) void deg_kernel(const int* __restrict__ dst,
                                                  const float* __restrict__ ew,
                                                  float* __restrict__ deg, int E) {
    int e = blockIdx.x * blockDim.x + threadIdx.x;
    if (e < E) atomicAdd(&deg[dst[e]], ew[e]);
}

__global__ __launch_bounds__(256) void dinv_kernel(float* __restrict__ deg, int n) {
    int i = blockIdx.x * blockDim.x + threadIdx.x;
    if (i < n) deg[i] = rsqrtf(deg[i] + 1.0f);
}

// ---------------- CSR build ----------------

__global__ __launch_bounds__(256) void count_kernel(const int* __restrict__ dst,
                                                    int* __restrict__ cnt, int E) {
    int e = blockIdx.x * blockDim.x + threadIdx.x;
    if (e < E) atomicAdd(&cnt[dst[e]], 1);
}

__global__ __launch_bounds__(512) void scan_block_kernel(const int* __restrict__ cnt,
                                                         int* __restrict__ rowptr,
                                                         int* __restrict__ bsums, int n) {
    __shared__ int s[512];
    int t = threadIdx.x;
    int i = blockIdx.x * 512 + t;
    s[t] = (i < n) ? cnt[i] : 0;
    __syncthreads();
    for (int off = 1; off < 512; off <<= 1) {
        int v = (t >= off) ? s[t - off] : 0;
        __syncthreads();
        s[t] += v;
        __syncthreads();
    }
    if (i < n) rowptr[i + 1] = s[t];
    if (t == 511) bsums[blockIdx.x] = s[511];
}

__global__ void scan_sums_kernel(int* bsums, int nb) {
    if (threadIdx.x == 0 && blockIdx.x == 0) {
        int run = 0;
        for (int i = 0; i < nb; ++i) { int v = bsums[i]; bsums[i] = run; run += v; }
    }
}

__global__ __launch_bounds__(512) void scan_add_kernel(int* __restrict__ rowptr,
                                                       const int* __restrict__ bsums, int n) {
    int i = blockIdx.x * 512 + threadIdx.x;
    if (i < n) rowptr[i + 1] += bsums[blockIdx.x];
    if (i == 0) rowptr[0] = 0;
}

__global__ __launch_bounds__(256) void fill_kernel(const int* __restrict__ src,
                                                   const int* __restrict__ dst,
                                                   const float* __restrict__ ew,
                                                   const float* __restrict__ dinv,
                                                   int* __restrict__ cursor,
                                                   int* __restrict__ col,
                                                   float* __restrict__ val, int E) {
    int e = blockIdx.x * blockDim.x + threadIdx.x;
    if (e >= E) return;
    int d = dst[e];
    int s = src[e];
    int pos = atomicAdd(&cursor[d], 1);
    col[pos] = s;
    val[pos] = dinv[s] * ew[e];
}

// ---------------- weight transpose + split:  W[K][N] f32 -> Th/Tl [N][K] bf16 ----------------

__global__ __launch_bounds__(256) void wsplit_kernel(const float* __restrict__ Wm,
                                                     unsigned short* __restrict__ Th,
                                                     unsigned short* __restrict__ Tl,
                                                     int K, int N) {
    int idx = blockIdx.x * blockDim.x + threadIdx.x;  // idx = n*K + k (write-coalesced)
    if (idx >= K * N) return;
    int n = idx / K, k = idx - n * K;
    float v = Wm[(size_t)k * N + n];
    unsigned short hi = f2bf(v);
    float res = v - bf2f(hi);
    Th[idx] = hi;
    Tl[idx] = f2bf(res);
}

// ---------------- CSR gather aggregation ----------------
// out[i] = dinv[i] * sum_e val_e * t[col_e] + dinv[i]^2 * t[i] (+bias) (relu?) (split?)

template <int C, bool BIAS, bool RELU, bool SPLIT>
__global__ __launch_bounds__(256) void gather_kernel(const float* __restrict__ t,
                                                     const int* __restrict__ rowptr,
                                                     const int* __restrict__ col,
                                                     const float* __restrict__ val,
                                                     const float* __restrict__ dinv,
                                                     const float* __restrict__ bias,
                                                     float* __restrict__ outf,
                                                     unsigned short* __restrict__ oh,
                                                     unsigned short* __restrict__ ol, int n) {
    constexpr int R = C / 64;
    int wave = threadIdx.x >> 6, lane = threadIdx.x & 63;
    for (int node = blockIdx.x * 4 + wave; node < n; node += gridDim.x * 4) {
        float acc[R];
#pragma unroll
        for (int r = 0; r < R; ++r) acc[r] = 0.f;
        int p0 = rowptr[node], p1 = rowptr[node + 1];
        for (int p = p0; p < p1; ++p) {
            int s = col[p];
            float a = val[p];
            const float* tr = t + (size_t)s * C;
#pragma unroll
            for (int r = 0; r < R; ++r) acc[r] += a * tr[r * 64 + lane];
        }
        float di = dinv[node];
        const float* tn = t + (size_t)node * C;
#pragma unroll
        for (int r = 0; r < R; ++r) {
            float v = di * acc[r] + di * di * tn[r * 64 + lane];
            if (BIAS) v += bias[r * 64 + lane];
            if (RELU) v = fmaxf(v, 0.f);
            size_t idx = (size_t)node * C + r * 64 + lane;
            if (SPLIT) {
                unsigned short hi = f2bf(v);
                float res = v - bf2f(hi);
                oh[idx] = hi;
                ol[idx] = f2bf(res);
            } else {
                outf[idx] = v;
            }
        }
    }
}

// ---------------- split-bf16 MFMA GEMM ----------------
// C[M_PAD][N] = A[M_PAD][K] * B[K][N], A given as hi/lo bf16 planes [M_PAD][K],
// B given as transposed hi/lo planes [N][K]. 3-pass split: Ah*Bh + Ah*Bl + Al*Bh.
// Block: 256 thr (4 waves), tile 128(M) x 128(N), BK=64. Wave tile 64x64.
// OUTMODE 0: Cf = acc (f32).  OUTMODE 1: split(relu(acc + bias)) -> Ch/Cl planes.

template <int OUTMODE>
__global__ __launch_bounds__(256, 2) void mfma_gemm(const unsigned short* __restrict__ Ah,
                                                    const unsigned short* __restrict__ Al,
                                                    const unsigned short* __restrict__ Bh,
                                                    const unsigned short* __restrict__ Bl,
                                                    const float* __restrict__ bias,
                                                    float* __restrict__ Cf,
                                                    unsigned short* __restrict__ Ch,
                                                    unsigned short* __restrict__ Cl,
                                                    int K, int N) {
    __shared__ unsigned short sAh[128 * 64];
    __shared__ unsigned short sAl[128 * 64];
    __shared__ unsigned short sBh[128 * 64];
    __shared__ unsigned short sBl[128 * 64];

    int tid = threadIdx.x;
    int lane = tid & 63, w = tid >> 6;
    int m0 = blockIdx.x * 128, n0 = blockIdx.y * 128;

    // staging assignment: wave w handles one plane
    const unsigned short* gsrc = (w == 0) ? Ah : (w == 1) ? Al : (w == 2) ? Bh : Bl;
    unsigned short* sbase = (w == 0) ? sAh : (w == 1) ? sAl : (w == 2) ? sBh : sBl;
    int grow0 = ((w < 2) ? m0 : n0) + (lane >> 3);
    int gcol = ((lane & 7) ^ ((lane >> 3) & 7)) * 8;  // inverse-swizzled source column
    const unsigned short* gptr0 = gsrc + (size_t)grow0 * K + gcol;

    float4_ acc[4][4] = {};

    int wm = (w >> 1) * 64, wn = (w & 1) * 64;
    int lr = lane & 15, lg = lane >> 4;

    for (int k0 = 0; k0 < K; k0 += 64) {
        const unsigned short* gp = gptr0 + k0;
#pragma unroll
        for (int q = 0; q < 16; ++q)
            GLOAD_LDS(gp + (size_t)(8 * q) * K, sbase + q * 512);
        __syncthreads();

#pragma unroll
        for (int ks = 0; ks < 2; ++ks) {
            short8 ahf[4], alf[4], bhf[4], blf[4];
#pragma unroll
            for (int f = 0; f < 4; ++f) {
                int ra = wm + f * 16 + lr;
                int sa = (((ks << 2) | lg) ^ (ra & 7)) * 16;
                ahf[f] = *(const short8*)((const char*)sAh + ra * 128 + sa);
                alf[f] = *(const short8*)((const char*)sAl + ra * 128 + sa);
                int rb = wn + f * 16 + lr;
                int sb = (((ks << 2) | lg) ^ (rb & 7)) * 16;
                bhf[f] = *(const short8*)((const char*)sBh + rb * 128 + sb);
                blf[f] = *(const short8*)((const char*)sBl + rb * 128 + sb);
            }
#pragma unroll
            for (int i = 0; i < 4; ++i)
#pragma unroll
                for (int j = 0; j < 4; ++j) {
                    acc[i][j] = __builtin_amdgcn_mfma_f32_16x16x32_bf16(ahf[i], bhf[j], acc[i][j], 0, 0, 0);
                    acc[i][j] = __builtin_amdgcn_mfma_f32_16x16x32_bf16(ahf[i], blf[j], acc[i][j], 0, 0, 0);
                    acc[i][j] = __builtin_amdgcn_mfma_f32_16x16x32_bf16(alf[i], bhf[j], acc[i][j], 0, 0, 0);
                }
        }
        __syncthreads();
    }

    // epilogue: C row = m0+wm+i*16+lg*4+r, col = n0+wn+j*16+lr  (m89-verified layout)
#pragma unroll
    for (int i = 0; i < 4; ++i) {
        int row0 = m0 + wm + i * 16 + lg * 4;
#pragma unroll
        for (int j = 0; j < 4; ++j) {
            int colg = n0 + wn + j * 16 + lr;
            float b = (OUTMODE == 1) ? bias[colg] : 0.f;
#pragma unroll
            for (int r = 0; r < 4; ++r) {
                float v = acc[i][j][r] + b;
                size_t idx = (size_t)(row0 + r) * N + colg;
                if (OUTMODE == 1) {
                    v = fmaxf(v, 0.f);
                    unsigned short hi = f2bf(v);
                    float res = v - bf2f(hi);
                    Ch[idx] = hi;
                    Cl[idx] = f2bf(res);
                } else {
                    Cf[idx] = v;
                }
            }
        }
    }
}

// ---------------- fused MLP head + softmax ----------------

__global__ __launch_bounds__(256) void mlp_kernel(const float* __restrict__ h,
                                                  const float* __restrict__ W1, const float* __restrict__ b1,
                                                  const float* __restrict__ W2, const float* __restrict__ b2,
                                                  const float* __restrict__ W3, const float* __restrict__ b3,
                                                  float* __restrict__ out, int n) {
    __shared__ float W1s[128 * 64];
    __shared__ float W2s[64 * 32];
    __shared__ float W3s[32 * 40];
    __shared__ float b1s[64], b2s[32], b3s[40];
    __shared__ float hs[4][128];
    __shared__ float h1s[4][64];
    __shared__ float h2s[4][32];
    __shared__ float ls[4][40];
    __shared__ float es[4][40];

    int tid = threadIdx.x;
    for (int i = tid; i < 128 * 64; i += 256) W1s[i] = W1[i];
    for (int i = tid; i < 64 * 32; i += 256) W2s[i] = W2[i];
    for (int i = tid; i < 32 * 40; i += 256) W3s[i] = W3[i];
    if (tid < 64) b1s[tid] = b1[tid];
    if (tid < 32) b2s[tid] = b2[tid];
    if (tid < 40) b3s[tid] = b3[tid];
    __syncthreads();

    int wave = tid >> 6, lane = tid & 63;

    for (int base = blockIdx.x * 4; base < n; base += gridDim.x * 4) {
        int node = base + wave;
        if (node < n) {
            hs[wave][lane]      = fmaxf(h[(size_t)node * 128 + lane], 0.f);
            hs[wave][lane + 64] = fmaxf(h[(size_t)node * 128 + lane + 64], 0.f);
        }
        __syncthreads();
        {
            float acc = b1s[lane];
#pragma unroll 8
            for (int k = 0; k < 128; ++k) acc += hs[wave][k] * W1s[k * 64 + lane];
            h1s[wave][lane] = fmaxf(acc, 0.f);
        }
        __syncthreads();
        if (lane < 32) {
            float acc = b2s[lane];
#pragma unroll 8
            for (int k = 0; k < 64; ++k) acc += h1s[wave][k] * W2s[k * 32 + lane];
            h2s[wave][lane] = fmaxf(acc, 0.f);
        }
        __syncthreads();
        if (lane < 40) {
            float acc = b3s[lane];
#pragma unroll 8
            for (int k = 0; k < 32; ++k) acc += h2s[wave][k] * W3s[k * 40 + lane];
            ls[wave][lane] = acc;
        }
        __syncthreads();
        float e = 0.f;
        if (lane < 40) {
            float m = -1e30f;
            for (int j = 0; j < 40; ++j) m = fmaxf(m, ls[wave][j]);
            e = expf(ls[wave][lane] - m);
            es[wave][lane] = e;
        }
        __syncthreads();
        if (node < n && lane < 40) {
            float s = 0.f;
            for (int j = 0; j < 40; ++j) s += es[wave][j];
            out[(size_t)node * 40 + lane] = e / s;
        }
        __syncthreads();
    }
}

// ---------------- launcher ----------------

extern "C" void kernel_launch(void* const* d_in, const int* in_sizes, int n_in,
                              void* d_out, int out_size, void* d_ws, size_t ws_size,
                              hipStream_t stream) {
    const float* x   = (const float*)d_in[0];
    const int*   ei  = (const int*)d_in[1];
    const float* ew  = (const float*)d_in[2];
    const float* W1  = (const float*)d_in[3];
    const float* b1  = (const float*)d_in[4];
    const float* W2  = (const float*)d_in[5];
    const float* b2  = (const float*)d_in[6];
    const float* W3  = (const float*)d_in[7];
    const float* b3  = (const float*)d_in[8];
    const float* L1w = (const float*)d_in[9];
    const float* L1b = (const float*)d_in[10];
    const float* L2w = (const float*)d_in[11];
    const float* L2b = (const float*)d_in[12];
    const float* L3w = (const float*)d_in[13];
    const float* L3b = (const float*)d_in[14];
    float* out = (float*)d_out;

    const int n = N_NODES, E = N_EDGES;
    const int* src = ei;
    const int* dst = ei + E;

    // ---- workspace layout (bytes) ----
    char* wsb = (char*)d_ws;
    size_t off = 0;
    auto alloc = [&](size_t bytes) -> char* {
        char* p = wsb + off;
        off += (bytes + 255) & ~(size_t)255;
        return p;
    };
    float* dinv   = (float*)alloc(N_NODES * 4);
    int* rowptr   = (int*)alloc((N_NODES + 1) * 4);
    int* cursor   = (int*)alloc(N_NODES * 4);
    int* colb     = (int*)alloc((size_t)N_EDGES * 4);
    float* val    = (float*)alloc((size_t)N_EDGES * 4);
    int* bsums    = (int*)alloc(256 * 4);
    unsigned short* W1th = (unsigned short*)alloc(512 * 128 * 2);
    unsigned short* W1tl = (unsigned short*)alloc(512 * 128 * 2);
    unsigned short* W2th = (unsigned short*)alloc(256 * 512 * 2);
    unsigned short* W2tl = (unsigned short*)alloc(256 * 512 * 2);
    unsigned short* W3th = (unsigned short*)alloc(128 * 256 * 2);
    unsigned short* W3tl = (unsigned short*)alloc(128 * 256 * 2);
    unsigned short* aggXh = (unsigned short*)alloc((size_t)M_PAD * 128 * 2);  // pool A
    unsigned short* aggXl = (unsigned short*)alloc((size_t)M_PAD * 128 * 2);
    unsigned short* h1h  = (unsigned short*)alloc((size_t)M_PAD * 512 * 2);   // pool B1
    unsigned short* h1l  = (unsigned short*)alloc((size_t)M_PAD * 512 * 2);   // pool B2
    float* t2     = (float*)alloc((size_t)M_PAD * 256 * 4);
    // aliases (lifetimes disjoint):
    unsigned short* agg2h = aggXh;                                   // aggX dead after GEMM L1 (25.6MB = both aggX planes)
    unsigned short* agg2l = (unsigned short*)h1h;                    // h1 dead after GEMM L2 (first half of h1h)
    float* t3   = (float*)((char*)h1h + (size_t)M_PAD * 256 * 2);    // second half of h1h
    float* agg3 = (float*)h1l;                                       // first 25.6MB of h1l

    const int nb = (n + 511) / 512;

    // deg / dinv
    hipMemsetAsync(dinv, 0, n * sizeof(float), stream);
    deg_kernel<<<(E + 255) / 256, 256, 0, stream>>>(dst, ew, dinv, E);
    dinv_kernel<<<(n + 255) / 256, 256, 0, stream>>>(dinv, n);

    // weight transpose+split (independent, cheap)
    wsplit_kernel<<<(128 * 512 + 255) / 256, 256, 0, stream>>>(W1, W1th, W1tl, 128, 512);
    wsplit_kernel<<<(512 * 256 + 255) / 256, 256, 0, stream>>>(W2, W2th, W2tl, 512, 256);
    wsplit_kernel<<<(256 * 128 + 255) / 256, 256, 0, stream>>>(W3, W3th, W3tl, 256, 128);

    // CSR build (by dst)
    hipMemsetAsync(cursor, 0, n * sizeof(int), stream);
    count_kernel<<<(E + 255) / 256, 256, 0, stream>>>(dst, cursor, E);
    scan_block_kernel<<<nb, 512, 0, stream>>>(cursor, rowptr, bsums, n);
    scan_sums_kernel<<<1, 64, 0, stream>>>(bsums, nb);
    scan_add_kernel<<<nb, 512, 0, stream>>>(rowptr, bsums, n);
    hipMemcpyAsync(cursor, rowptr, n * sizeof(int), hipMemcpyDeviceToDevice, stream);
    fill_kernel<<<(E + 255) / 256, 256, 0, stream>>>(src, dst, ew, dinv, cursor, colb, val, E);

    // ----- layer 1: aggX = A_hat x (split) ; h1 = split(relu(aggX@W1 + b1))
    gather_kernel<128, false, false, true><<<(n + 3) / 4, 256, 0, stream>>>(
        x, rowptr, colb, val, dinv, nullptr, nullptr, aggXh, aggXl, n);
    {
        dim3 g(M_PAD / 128, 512 / 128);
        mfma_gemm<1><<<g, 256, 0, stream>>>(aggXh, aggXl, W1th, W1tl, b1, nullptr, h1h, h1l, 128, 512);
    }
    // ----- layer 2: t2 = h1 @ W2 (f32) ; agg2 = split(relu(A_hat t2 + b2))
    {
        dim3 g(M_PAD / 128, 256 / 128);
        mfma_gemm<0><<<g, 256, 0, stream>>>(h1h, h1l, W2th, W2tl, nullptr, t2, nullptr, nullptr, 512, 256);
    }
    gather_kernel<256, true, true, true><<<(n + 3) / 4, 256, 0, stream>>>(
        t2, rowptr, colb, val, dinv, b2, nullptr, agg2h, agg2l, n);
    // ----- layer 3: t3 = relu(agg2) @ W3 (f32) ; agg3 = A_hat t3 + b3 (f32)
    {
        dim3 g(M_PAD / 128, 128 / 128);
        mfma_gemm<0><<<g, 256, 0, stream>>>(agg2h, agg2l, W3th, W3tl, nullptr, t3, nullptr, nullptr, 256, 128);
    }
    gather_kernel<128, true, false, false><<<(n + 3) / 4, 256, 0, stream>>>(
        t3, rowptr, colb, val, dinv, b3, agg3, nullptr, nullptr, n);
    // ----- MLP head + softmax
    mlp_kernel<<<1024, 256, 0, stream>>>(agg3, L1w, L1b, L2w, L2b, L3w, L3b, out, n);
}

// Round 5
// 715.378 us; speedup vs baseline: 8.2894x; 1.0651x over previous
//
#include <hip/hip_runtime.h>
#include <hip/hip_bf16.h>

#define N_NODES 50000
#define N_EDGES 800000
#define M_PAD 50048  // 391 * 128

typedef __attribute__((ext_vector_type(8))) short short8;
typedef __attribute__((ext_vector_type(4))) float float4_;

#define GLOAD_LDS(g, l) __builtin_amdgcn_global_load_lds( \
    (const __attribute__((address_space(1))) void*)(g),   \
    (__attribute__((address_space(3))) void*)(l), 16, 0, 0)

__device__ __forceinline__ unsigned short f2bf(float f) {
    unsigned int u = __float_as_uint(f);
    unsigned int r = (u + 0x7FFFu + ((u >> 16) & 1u)) >> 16;
    return (unsigned short)r;
}
__device__ __forceinline__ float bf2f(unsigned short h) {
    return __uint_as_float(((unsigned int)h) << 16);
}

// ---------------- degree / normalization ----------------

__global__ __launch_bounds__(256) void deg_kernel(const int* __restrict__ dst,
                                                  const float* __restrict__ ew,
                                                  float* __restrict__ deg, int E) {
    int e = blockIdx.x * blockDim.x + threadIdx.x;
    if (e < E) atomicAdd(&deg[dst[e]], ew[e]);
}

__global__ __launch_bounds__(256) void dinv_kernel(float* __restrict__ deg, int n) {
    int i = blockIdx.x * blockDim.x + threadIdx.x;
    if (i < n) deg[i] = rsqrtf(deg[i] + 1.0f);
}

// ---------------- CSR build ----------------

__global__ __launch_bounds__(256) void count_kernel(const int* __restrict__ dst,
                                                    int* __restrict__ cnt, int E) {
    int e = blockIdx.x * blockDim.x + threadIdx.x;
    if (e < E) atomicAdd(&cnt[dst[e]], 1);
}

__global__ __launch_bounds__(512) void scan_block_kernel(const int* __restrict__ cnt,
                                                         int* __restrict__ rowptr,
                                                         int* __restrict__ bsums, int n) {
    __shared__ int s[512];
    int t = threadIdx.x;
    int i = blockIdx.x * 512 + t;
    s[t] = (i < n) ? cnt[i] : 0;
    __syncthreads();
    for (int off = 1; off < 512; off <<= 1) {
        int v = (t >= off) ? s[t - off] : 0;
        __syncthreads();
        s[t] += v;
        __syncthreads();
    }
    if (i < n) rowptr[i + 1] = s[t];
    if (t == 511) bsums[blockIdx.x] = s[511];
}

__global__ void scan_sums_kernel(int* bsums, int nb) {
    if (threadIdx.x == 0 && blockIdx.x == 0) {
        int run = 0;
        for (int i = 0; i < nb; ++i) { int v = bsums[i]; bsums[i] = run; run += v; }
    }
}

__global__ __launch_bounds__(512) void scan_add_kernel(int* __restrict__ rowptr,
                                                       const int* __restrict__ bsums, int n) {
    int i = blockIdx.x * 512 + threadIdx.x;
    if (i < n) rowptr[i + 1] += bsums[blockIdx.x];
    if (i == 0) rowptr[0] = 0;
}

__global__ __launch_bounds__(256) void fill_kernel(const int* __restrict__ src,
                                                   const int* __restrict__ dst,
                                                   const float* __restrict__ ew,
                                                   const float* __restrict__ dinv,
                                                   int* __restrict__ cursor,
                                                   int* __restrict__ col,
                                                   float* __restrict__ val, int E) {
    int e = blockIdx.x * blockDim.x + threadIdx.x;
    if (e >= E) return;
    int d = dst[e];
    int s = src[e];
    int pos = atomicAdd(&cursor[d], 1);
    col[pos] = s;
    val[pos] = dinv[s] * ew[e];
}

// ---------------- weight transpose + split:  W[K][N] f32 -> Th/Tl [N][K] bf16 ----------------

__global__ __launch_bounds__(256) void wsplit_kernel(const float* __restrict__ Wm,
                                                     unsigned short* __restrict__ Th,
                                                     unsigned short* __restrict__ Tl,
                                                     int K, int N) {
    int idx = blockIdx.x * blockDim.x + threadIdx.x;  // idx = n*K + k (write-coalesced)
    if (idx >= K * N) return;
    int n = idx / K, k = idx - n * K;
    float v = Wm[(size_t)k * N + n];
    unsigned short hi = f2bf(v);
    float res = v - bf2f(hi);
    Th[idx] = hi;
    Tl[idx] = f2bf(res);
}

// ---------------- CSR gather aggregation (MLP-optimized) ----------------
// out[i] = dinv[i] * sum_e val_e * t[col_e] + dinv[i]^2 * t[i] (+bias) (relu?) (split?)
// One wave per node. Lane covers float4 chunk li of the row; for C=128 two edges
// are processed per step (lane halves) and combined with shfl_xor(32).
// Edge loop unrolled x4 with clamped unconditional metadata loads -> 4 (C=256)
// or 8 (C=128) independent row loads in flight per wave.

template <int C, bool BIAS, bool RELU, bool SPLIT>
__global__ __launch_bounds__(256) void gather_kernel(const float* __restrict__ t,
                                                     const int* __restrict__ rowptr,
                                                     const int* __restrict__ col,
                                                     const float* __restrict__ val,
                                                     const float* __restrict__ dinv,
                                                     const float* __restrict__ bias,
                                                     float* __restrict__ outf,
                                                     unsigned short* __restrict__ oh,
                                                     unsigned short* __restrict__ ol, int n) {
    constexpr int L = C / 4;      // lanes covering one row in float4s (32 or 64)
    constexpr int EPS = 64 / L;   // edge slots per step (2 or 1)
    constexpr int U = 4;          // unroll depth
    int wave = threadIdx.x >> 6, lane = threadIdx.x & 63;
    int slot = lane / L, li = lane % L;

    for (int node = blockIdx.x * 4 + wave; node < n; node += gridDim.x * 4) {
        int p0 = rowptr[node], p1 = rowptr[node + 1];
        float4 acc = {0.f, 0.f, 0.f, 0.f};
        for (int pb = p0; pb < p1; pb += U * EPS) {
            float a[U];
            float4 v[U];
#pragma unroll
            for (int u = 0; u < U; ++u) {
                int pe = pb + u * EPS + slot;
                int pec = min(pe, p1 - 1);          // clamped: unconditional loads
                int s = col[pec];
                float av = val[pec];
                a[u] = (pe < p1) ? av : 0.f;        // mask coefficient only
                v[u] = *(const float4*)(t + (size_t)s * C + li * 4);
            }
#pragma unroll
            for (int u = 0; u < U; ++u) {
                acc.x += a[u] * v[u].x;
                acc.y += a[u] * v[u].y;
                acc.z += a[u] * v[u].z;
                acc.w += a[u] * v[u].w;
            }
        }
        if (EPS == 2) {
            acc.x += __shfl_xor(acc.x, 32);
            acc.y += __shfl_xor(acc.y, 32);
            acc.z += __shfl_xor(acc.z, 32);
            acc.w += __shfl_xor(acc.w, 32);
        }
        if (EPS == 1 || slot == 0) {
            float di = dinv[node];
            float s2 = di * di;
            float4 tv = *(const float4*)(t + (size_t)node * C + li * 4);
            float4 r;
            r.x = di * acc.x + s2 * tv.x;
            r.y = di * acc.y + s2 * tv.y;
            r.z = di * acc.z + s2 * tv.z;
            r.w = di * acc.w + s2 * tv.w;
            if (BIAS) {
                float4 b4 = *(const float4*)(bias + li * 4);
                r.x += b4.x; r.y += b4.y; r.z += b4.z; r.w += b4.w;
            }
            if (RELU) {
                r.x = fmaxf(r.x, 0.f); r.y = fmaxf(r.y, 0.f);
                r.z = fmaxf(r.z, 0.f); r.w = fmaxf(r.w, 0.f);
            }
            size_t base = (size_t)node * C + li * 4;
            if (SPLIT) {
                ushort4 h4, l4;
                float rv[4] = {r.x, r.y, r.z, r.w};
                unsigned short hs[4], lsx[4];
#pragma unroll
                for (int j = 0; j < 4; ++j) {
                    unsigned short hi = f2bf(rv[j]);
                    hs[j] = hi;
                    lsx[j] = f2bf(rv[j] - bf2f(hi));
                }
                h4.x = hs[0]; h4.y = hs[1]; h4.z = hs[2]; h4.w = hs[3];
                l4.x = lsx[0]; l4.y = lsx[1]; l4.z = lsx[2]; l4.w = lsx[3];
                *(ushort4*)(oh + base) = h4;
                *(ushort4*)(ol + base) = l4;
            } else {
                *(float4*)(outf + base) = r;
            }
        }
    }
}

// ---------------- split-bf16 MFMA GEMM ----------------
// C[M_PAD][N] = A[M_PAD][K] * B[K][N], A given as hi/lo bf16 planes [M_PAD][K],
// B given as transposed hi/lo planes [N][K]. 3-pass split: Ah*Bh + Ah*Bl + Al*Bh.
// Block: 256 thr (4 waves), tile 128(M) x 128(N), BK=64. Wave tile 64x64.
// OUTMODE 0: Cf = acc (f32).  OUTMODE 1: split(relu(acc + bias)) -> Ch/Cl planes.

template <int OUTMODE>
__global__ __launch_bounds__(256, 2) void mfma_gemm(const unsigned short* __restrict__ Ah,
                                                    const unsigned short* __restrict__ Al,
                                                    const unsigned short* __restrict__ Bh,
                                                    const unsigned short* __restrict__ Bl,
                                                    const float* __restrict__ bias,
                                                    float* __restrict__ Cf,
                                                    unsigned short* __restrict__ Ch,
                                                    unsigned short* __restrict__ Cl,
                                                    int K, int N) {
    __shared__ unsigned short sAh[128 * 64];
    __shared__ unsigned short sAl[128 * 64];
    __shared__ unsigned short sBh[128 * 64];
    __shared__ unsigned short sBl[128 * 64];

    int tid = threadIdx.x;
    int lane = tid & 63, w = tid >> 6;
    int m0 = blockIdx.x * 128, n0 = blockIdx.y * 128;

    // staging assignment: wave w handles one plane
    const unsigned short* gsrc = (w == 0) ? Ah : (w == 1) ? Al : (w == 2) ? Bh : Bl;
    unsigned short* sbase = (w == 0) ? sAh : (w == 1) ? sAl : (w == 2) ? sBh : sBl;
    int grow0 = ((w < 2) ? m0 : n0) + (lane >> 3);
    int gcol = ((lane & 7) ^ ((lane >> 3) & 7)) * 8;  // inverse-swizzled source column
    const unsigned short* gptr0 = gsrc + (size_t)grow0 * K + gcol;

    float4_ acc[4][4] = {};

    int wm = (w >> 1) * 64, wn = (w & 1) * 64;
    int lr = lane & 15, lg = lane >> 4;

    for (int k0 = 0; k0 < K; k0 += 64) {
        const unsigned short* gp = gptr0 + k0;
#pragma unroll
        for (int q = 0; q < 16; ++q)
            GLOAD_LDS(gp + (size_t)(8 * q) * K, sbase + q * 512);
        __syncthreads();

#pragma unroll
        for (int ks = 0; ks < 2; ++ks) {
            short8 ahf[4], alf[4], bhf[4], blf[4];
#pragma unroll
            for (int f = 0; f < 4; ++f) {
                int ra = wm + f * 16 + lr;
                int sa = (((ks << 2) | lg) ^ (ra & 7)) * 16;
                ahf[f] = *(const short8*)((const char*)sAh + ra * 128 + sa);
                alf[f] = *(const short8*)((const char*)sAl + ra * 128 + sa);
                int rb = wn + f * 16 + lr;
                int sb = (((ks << 2) | lg) ^ (rb & 7)) * 16;
                bhf[f] = *(const short8*)((const char*)sBh + rb * 128 + sb);
                blf[f] = *(const short8*)((const char*)sBl + rb * 128 + sb);
            }
#pragma unroll
            for (int i = 0; i < 4; ++i)
#pragma unroll
                for (int j = 0; j < 4; ++j) {
                    acc[i][j] = __builtin_amdgcn_mfma_f32_16x16x32_bf16(ahf[i], bhf[j], acc[i][j], 0, 0, 0);
                    acc[i][j] = __builtin_amdgcn_mfma_f32_16x16x32_bf16(ahf[i], blf[j], acc[i][j], 0, 0, 0);
                    acc[i][j] = __builtin_amdgcn_mfma_f32_16x16x32_bf16(alf[i], bhf[j], acc[i][j], 0, 0, 0);
                }
        }
        __syncthreads();
    }

    // epilogue: C row = m0+wm+i*16+lg*4+r, col = n0+wn+j*16+lr  (m89-verified layout)
#pragma unroll
    for (int i = 0; i < 4; ++i) {
        int row0 = m0 + wm + i * 16 + lg * 4;
#pragma unroll
        for (int j = 0; j < 4; ++j) {
            int colg = n0 + wn + j * 16 + lr;
            float b = (OUTMODE == 1) ? bias[colg] : 0.f;
#pragma unroll
            for (int r = 0; r < 4; ++r) {
                float v = acc[i][j][r] + b;
                size_t idx = (size_t)(row0 + r) * N + colg;
                if (OUTMODE == 1) {
                    v = fmaxf(v, 0.f);
                    unsigned short hi = f2bf(v);
                    float res = v - bf2f(hi);
                    Ch[idx] = hi;
                    Cl[idx] = f2bf(res);
                } else {
                    Cf[idx] = v;
                }
            }
        }
    }
}

// ---------------- fused MLP head + softmax ----------------

__global__ __launch_bounds__(256) void mlp_kernel(const float* __restrict__ h,
                                                  const float* __restrict__ W1, const float* __restrict__ b1,
                                                  const float* __restrict__ W2, const float* __restrict__ b2,
                                                  const float* __restrict__ W3, const float* __restrict__ b3,
                                                  float* __restrict__ out, int n) {
    __shared__ float W1s[128 * 64];
    __shared__ float W2s[64 * 32];
    __shared__ float W3s[32 * 40];
    __shared__ float b1s[64], b2s[32], b3s[40];
    __shared__ float hs[4][128];
    __shared__ float h1s[4][64];
    __shared__ float h2s[4][32];
    __shared__ float ls[4][40];
    __shared__ float es[4][40];

    int tid = threadIdx.x;
    for (int i = tid; i < 128 * 64; i += 256) W1s[i] = W1[i];
    for (int i = tid; i < 64 * 32; i += 256) W2s[i] = W2[i];
    for (int i = tid; i < 32 * 40; i += 256) W3s[i] = W3[i];
    if (tid < 64) b1s[tid] = b1[tid];
    if (tid < 32) b2s[tid] = b2[tid];
    if (tid < 40) b3s[tid] = b3[tid];
    __syncthreads();

    int wave = tid >> 6, lane = tid & 63;

    for (int base = blockIdx.x * 4; base < n; base += gridDim.x * 4) {
        int node = base + wave;
        if (node < n) {
            hs[wave][lane]      = fmaxf(h[(size_t)node * 128 + lane], 0.f);
            hs[wave][lane + 64] = fmaxf(h[(size_t)node * 128 + lane + 64], 0.f);
        }
        __syncthreads();
        {
            float acc = b1s[lane];
#pragma unroll 8
            for (int k = 0; k < 128; ++k) acc += hs[wave][k] * W1s[k * 64 + lane];
            h1s[wave][lane] = fmaxf(acc, 0.f);
        }
        __syncthreads();
        if (lane < 32) {
            float acc = b2s[lane];
#pragma unroll 8
            for (int k = 0; k < 64; ++k) acc += h1s[wave][k] * W2s[k * 32 + lane];
            h2s[wave][lane] = fmaxf(acc, 0.f);
        }
        __syncthreads();
        if (lane < 40) {
            float acc = b3s[lane];
#pragma unroll 8
            for (int k = 0; k < 32; ++k) acc += h2s[wave][k] * W3s[k * 40 + lane];
            ls[wave][lane] = acc;
        }
        __syncthreads();
        float e = 0.f;
        if (lane < 40) {
            float m = -1e30f;
            for (int j = 0; j < 40; ++j) m = fmaxf(m, ls[wave][j]);
            e = expf(ls[wave][lane] - m);
            es[wave][lane] = e;
        }
        __syncthreads();
        if (node < n && lane < 40) {
            float s = 0.f;
            for (int j = 0; j < 40; ++j) s += es[wave][j];
            out[(size_t)node * 40 + lane] = e / s;
        }
        __syncthreads();
    }
}

// ---------------- launcher ----------------

extern "C" void kernel_launch(void* const* d_in, const int* in_sizes, int n_in,
                              void* d_out, int out_size, void* d_ws, size_t ws_size,
                              hipStream_t stream) {
    const float* x   = (const float*)d_in[0];
    const int*   ei  = (const int*)d_in[1];
    const float* ew  = (const float*)d_in[2];
    const float* W1  = (const float*)d_in[3];
    const float* b1  = (const float*)d_in[4];
    const float* W2  = (const float*)d_in[5];
    const float* b2  = (const float*)d_in[6];
    const float* W3  = (const float*)d_in[7];
    const float* b3  = (const float*)d_in[8];
    const float* L1w = (const float*)d_in[9];
    const float* L1b = (const float*)d_in[10];
    const float* L2w = (const float*)d_in[11];
    const float* L2b = (const float*)d_in[12];
    const float* L3w = (const float*)d_in[13];
    const float* L3b = (const float*)d_in[14];
    float* out = (float*)d_out;

    const int n = N_NODES, E = N_EDGES;
    const int* src = ei;
    const int* dst = ei + E;

    // ---- workspace layout (bytes) ----
    char* wsb = (char*)d_ws;
    size_t off = 0;
    auto alloc = [&](size_t bytes) -> char* {
        char* p = wsb + off;
        off += (bytes + 255) & ~(size_t)255;
        return p;
    };
    float* dinv   = (float*)alloc(N_NODES * 4);
    int* rowptr   = (int*)alloc((N_NODES + 1) * 4);
    int* cursor   = (int*)alloc(N_NODES * 4);
    int* colb     = (int*)alloc((size_t)N_EDGES * 4);
    float* val    = (float*)alloc((size_t)N_EDGES * 4);
    int* bsums    = (int*)alloc(256 * 4);
    unsigned short* W1th = (unsigned short*)alloc(512 * 128 * 2);
    unsigned short* W1tl = (unsigned short*)alloc(512 * 128 * 2);
    unsigned short* W2th = (unsigned short*)alloc(256 * 512 * 2);
    unsigned short* W2tl = (unsigned short*)alloc(256 * 512 * 2);
    unsigned short* W3th = (unsigned short*)alloc(128 * 256 * 2);
    unsigned short* W3tl = (unsigned short*)alloc(128 * 256 * 2);
    unsigned short* aggXh = (unsigned short*)alloc((size_t)M_PAD * 128 * 2);  // pool A
    unsigned short* aggXl = (unsigned short*)alloc((size_t)M_PAD * 128 * 2);
    unsigned short* h1h  = (unsigned short*)alloc((size_t)M_PAD * 512 * 2);   // pool B1
    unsigned short* h1l  = (unsigned short*)alloc((size_t)M_PAD * 512 * 2);   // pool B2
    float* t2     = (float*)alloc((size_t)M_PAD * 256 * 4);
    // aliases (lifetimes disjoint):
    unsigned short* agg2h = aggXh;                                   // aggX dead after GEMM L1 (25.6MB = both aggX planes)
    unsigned short* agg2l = (unsigned short*)h1h;                    // h1 dead after GEMM L2 (first half of h1h)
    float* t3   = (float*)((char*)h1h + (size_t)M_PAD * 256 * 2);    // second half of h1h
    float* agg3 = (float*)h1l;                                       // first 25.6MB of h1l

    const int nb = (n + 511) / 512;

    // deg / dinv
    hipMemsetAsync(dinv, 0, n * sizeof(float), stream);
    deg_kernel<<<(E + 255) / 256, 256, 0, stream>>>(dst, ew, dinv, E);
    dinv_kernel<<<(n + 255) / 256, 256, 0, stream>>>(dinv, n);

    // weight transpose+split (independent, cheap)
    wsplit_kernel<<<(128 * 512 + 255) / 256, 256, 0, stream>>>(W1, W1th, W1tl, 128, 512);
    wsplit_kernel<<<(512 * 256 + 255) / 256, 256, 0, stream>>>(W2, W2th, W2tl, 512, 256);
    wsplit_kernel<<<(256 * 128 + 255) / 256, 256, 0, stream>>>(W3, W3th, W3tl, 256, 128);

    // CSR build (by dst)
    hipMemsetAsync(cursor, 0, n * sizeof(int), stream);
    count_kernel<<<(E + 255) / 256, 256, 0, stream>>>(dst, cursor, E);
    scan_block_kernel<<<nb, 512, 0, stream>>>(cursor, rowptr, bsums, n);
    scan_sums_kernel<<<1, 64, 0, stream>>>(bsums, nb);
    scan_add_kernel<<<nb, 512, 0, stream>>>(rowptr, bsums, n);
    hipMemcpyAsync(cursor, rowptr, n * sizeof(int), hipMemcpyDeviceToDevice, stream);
    fill_kernel<<<(E + 255) / 256, 256, 0, stream>>>(src, dst, ew, dinv, cursor, colb, val, E);

    // ----- layer 1: aggX = A_hat x (split) ; h1 = split(relu(aggX@W1 + b1))
    gather_kernel<128, false, false, true><<<(n + 3) / 4, 256, 0, stream>>>(
        x, rowptr, colb, val, dinv, nullptr, nullptr, aggXh, aggXl, n);
    {
        dim3 g(M_PAD / 128, 512 / 128);
        mfma_gemm<1><<<g, 256, 0, stream>>>(aggXh, aggXl, W1th, W1tl, b1, nullptr, h1h, h1l, 128, 512);
    }
    // ----- layer 2: t2 = h1 @ W2 (f32) ; agg2 = split(relu(A_hat t2 + b2))
    {
        dim3 g(M_PAD / 128, 256 / 128);
        mfma_gemm<0><<<g, 256, 0, stream>>>(h1h, h1l, W2th, W2tl, nullptr, t2, nullptr, nullptr, 512, 256);
    }
    gather_kernel<256, true, true, true><<<(n + 3) / 4, 256, 0, stream>>>(
        t2, rowptr, colb, val, dinv, b2, nullptr, agg2h, agg2l, n);
    // ----- layer 3: t3 = relu(agg2) @ W3 (f32) ; agg3 = A_hat t3 + b3 (f32)
    {
        dim3 g(M_PAD / 128, 128 / 128);
        mfma_gemm<0><<<g, 256, 0, stream>>>(agg2h, agg2l, W3th, W3tl, nullptr, t3, nullptr, nullptr, 256, 128);
    }
    gather_kernel<128, true, false, false><<<(n + 3) / 4, 256, 0, stream>>>(
        t3, rowptr, colb, val, dinv, b3, agg3, nullptr, nullptr, n);
    // ----- MLP head + softmax
    mlp_kernel<<<1024, 256, 0, stream>>>(agg3, L1w, L1b, L2w, L2b, L3w, L3b, out, n);
}